// Round 5
// baseline (646.830 us; speedup 1.0000x reference)
//
#include <hip/hip_runtime.h>
#include <math.h>

// Keep all float arithmetic un-contracted (separate mul/add like the numpy/jax
// f32 reference) so discrete decisions (argmax, top-k order, iou>thr) match.
#pragma clang fp contract(off)

// ---------------- problem constants ----------------
#define BB      8
#define AA      9
#define NCLS    80
#define NTOT    72000      // 57600 + 14400 boxes per image
#define PRE     1000
#define POST    300
#define CAP     4096
#define NBINS   65536
#define BCLIP   4.135166556742356f   // log(1000/16)
#define NBLK0   1440       // 72 slabs * 5 cgroups * 4 hw-quarters
#define NBLK1   360        // 72 slabs * 5 cgroups
#define DS1BASE 1843200    // float offset of branch1 delta staging (72*4*6400)

__device__ __constant__ float c_sizes[9] = {16.f,32.f,64.f,20.f,40.f,80.f,24.f,48.f,96.f};

__device__ inline unsigned fkey(float s) {
    unsigned u = __float_as_uint(s);
    return (u & 0x80000000u) ? ~u : (u | 0x80000000u);
}
__device__ inline float unfkey(unsigned u) {
    return __uint_as_float((u & 0x80000000u) ? (u ^ 0x80000000u) : ~u);
}

// ---------------- kernel A: contiguous stream + LDS class-max reduction --------
// Block owns (slab=(b,a), class-group cg, hw-chunk). Reads its rows CONTIGUOUSLY
// (channel rows of one slab are adjacent in memory), 8-deep float4 batches.
// Class-max via LDS atomicMax on packed key (fkey<<32)|~cls  (first-max tiebreak).
// Delta channels (c<4, cg0 only) staged to dstage. Partial keys -> global.
template<int BR>
__device__ inline void stream_impl(int bx, const float* __restrict__ data,
                                   unsigned long long* __restrict__ partial,
                                   float* __restrict__ dstage,
                                   unsigned long long* lkey)
{
    constexpr int ROWF4 = BR ? 400 : 1600;   // row length in float4
    int slab, cg, hwq;
    if (BR == 0) { slab = bx / 20; int r = bx % 20; cg = r / 4; hwq = r % 4; }
    else         { slab = bx / 5;  cg = bx % 5;  hwq = 0; }
    int b = slab / 9, a = slab - (slab / 9) * 9;
    int nch = cg ? 16 : 20;
    int c_first = cg ? (4 + cg * 16) : 0;
    int N = nch * 400;

    for (int i = threadIdx.x; i < 1600; i += 256) lkey[i] = 0ULL;
    __syncthreads();

    const float4* d4 = (const float4*)data;
    size_t rowbase = (size_t)(b * 756 + a * 84 + c_first) * ROWF4 + hwq * 400;
    float4* ds4 = (float4*)dstage;

    for (int i = threadIdx.x; i < N; i += 2048) {
        float4 v[8]; int cl[8], rr[8];
        #pragma unroll
        for (int u = 0; u < 8; u++) {
            int idx = i + u * 256;
            int c_local = idx / 400;
            cl[u] = c_local; rr[u] = idx - c_local * 400;
            if (idx < N)
                v[u] = d4[rowbase + (size_t)c_local * ROWF4 + rr[u]];
        }
        #pragma unroll
        for (int u = 0; u < 8; u++) {
            int idx = i + u * 256;
            if (idx < N) {
                int ch = c_first + cl[u];
                if (ch < 4) {
                    size_t di = BR ? (size_t)(DS1BASE / 4) + (size_t)(slab * 4 + ch) * 400 + rr[u]
                                   : (size_t)(slab * 4 + ch) * 1600 + hwq * 400 + rr[u];
                    ds4[di] = v[u];
                } else {
                    unsigned icls = ~(unsigned)(ch - 4);
                    int cell = rr[u] * 4;
                    atomicMax(&lkey[cell + 0], ((unsigned long long)fkey(v[u].x) << 32) | icls);
                    atomicMax(&lkey[cell + 1], ((unsigned long long)fkey(v[u].y) << 32) | icls);
                    atomicMax(&lkey[cell + 2], ((unsigned long long)fkey(v[u].z) << 32) | icls);
                    atomicMax(&lkey[cell + 3], ((unsigned long long)fkey(v[u].w) << 32) | icls);
                }
            }
        }
    }
    __syncthreads();

    size_t pbase = (size_t)cg * 576000 + (size_t)b * 72000
                 + (BR ? (size_t)(57600 + a * 1600) : (size_t)(a * 6400 + hwq * 1600));
    for (int cell = threadIdx.x; cell < 1600; cell += 256)
        partial[pbase + cell] = lkey[cell];
}

__global__ __launch_bounds__(256) void k_stream(
    const float* __restrict__ data0, const float* __restrict__ data1,
    unsigned long long* __restrict__ partial, float* __restrict__ dstage)
{
    __shared__ unsigned long long lkey[1600];
    int bx = blockIdx.x;
    if (bx < NBLK0) stream_impl<0>(bx, data0, partial, dstage, lkey);
    else            stream_impl<1>(bx - NBLK0, data1, partial, dstage, lkey);
}

// ---------------- kernel B: merge partials + decode + histogram ----------------
__global__ __launch_bounds__(256) void k_cells(
    const unsigned long long* __restrict__ partial, const float* __restrict__ dstage,
    float* __restrict__ boxes, float* __restrict__ scores, float* __restrict__ cls,
    unsigned* __restrict__ hist)
{
    int t = blockIdx.x * 256 + threadIdx.x;      // pair index (2 cells)
    if (t >= 288000) return;
    int b = t / 36000;
    int mm = t - b * 36000;

    const ulonglong2* p2 = (const ulonglong2*)partial;
    ulonglong2 best = p2[(size_t)b * 36000 + mm];
    #pragma unroll
    for (int g = 1; g < 5; g++) {
        ulonglong2 v = p2[(size_t)g * 288000 + (size_t)b * 36000 + mm];
        if (v.x > best.x) best.x = v.x;
        if (v.y > best.y) best.y = v.y;
    }
    unsigned long long kk[2] = { best.x, best.y };

    int m0 = mm * 2;
    int a, hw, W, STRIDE;
    size_t dbase;
    if (m0 < 57600) {
        a = m0 / 6400; hw = m0 - a * 6400; W = 80; STRIDE = 8;
        dbase = (size_t)((b * 9 + a) * 4) * 6400 + hw;
        // deltas at dbase + c*6400
    } else {
        int m1 = m0 - 57600;
        a = m1 / 1600; hw = m1 - a * 1600; W = 40; STRIDE = 16;
        dbase = (size_t)DS1BASE + (size_t)((b * 9 + a) * 4) * 1600 + hw;
    }
    size_t cstride = (m0 < 57600) ? 6400 : 1600;
    float2 dx = *(const float2*)(dstage + dbase);
    float2 dy = *(const float2*)(dstage + dbase + cstride);
    float2 dw = *(const float2*)(dstage + dbase + 2 * cstride);
    float2 dh = *(const float2*)(dstage + dbase + 3 * cstride);
    float dxa[2] = {dx.x, dx.y}, dya[2] = {dy.x, dy.y};
    float dwa[2] = {dw.x, dw.y}, dha[2] = {dh.x, dh.y};

    float sz = c_sizes[a];
    size_t o = (size_t)b * NTOT + m0;

    #pragma unroll
    for (int k = 0; k < 2; k++) {
        int hwk = hw + k;
        int h = hwk / W;
        int w = hwk - h * W;
        float cy = (h + 0.5f) * (float)STRIDE;
        float cx = (w + 0.5f) * (float)STRIDE;
        float pcx = dxa[k] * sz + cx;
        float pcy = dya[k] * sz + cy;
        float pw  = expf(fminf(dwa[k], BCLIP)) * sz;
        float ph  = expf(fminf(dha[k], BCLIP)) * sz;
        float x1 = fminf(fmaxf(pcx - 0.5f * pw, 0.f), 640.f);
        float y1 = fminf(fmaxf(pcy - 0.5f * ph, 0.f), 640.f);
        float x2 = fminf(fmaxf(pcx + 0.5f * pw, 0.f), 640.f);
        float y2 = fminf(fmaxf(pcy + 0.5f * ph, 0.f), 640.f);
        ((float4*)boxes)[o + k] = make_float4(x1, y1, x2, y2);
        scores[o + k] = unfkey((unsigned)(kk[k] >> 32));
        cls[o + k]    = (float)(~(unsigned)kk[k]);
        atomicAdd(&hist[(size_t)b * NBINS + (unsigned)(kk[k] >> 48)], 1u);
    }
}

// ---------------- kernel C1: coarse histogram sums (64 blocks) ----------------
__global__ __launch_bounds__(256) void k_hsum(const unsigned* __restrict__ hist,
                                              unsigned* __restrict__ coarse)
{
    int img = blockIdx.x >> 3, seg = blockIdx.x & 7;
    int tid = threadIdx.x;
    int cb = tid >> 3, part = tid & 7;
    const uint4* h4 = (const uint4*)hist;
    size_t base = (size_t)img * 16384 + seg * 2048 + cb * 64 + part * 8;
    unsigned s = 0;
    #pragma unroll
    for (int i = 0; i < 8; i++) {
        uint4 v = h4[base + i];
        s += v.x + v.y + v.z + v.w;
    }
    s += __shfl_xor(s, 1);
    s += __shfl_xor(s, 2);
    s += __shfl_xor(s, 4);
    if (part == 0) coarse[img * 256 + seg * 32 + cb] = s;
}

// ---------------- kernel C2: per-image 16-bit threshold bucket ----------------
__global__ __launch_bounds__(256) void k_thresh(const unsigned* __restrict__ hist,
                                                const unsigned* __restrict__ coarse,
                                                unsigned* __restrict__ T)
{
    __shared__ unsigned S[256];
    __shared__ int Csh;
    __shared__ unsigned cumAbove;
    int b = blockIdx.x, tid = threadIdx.x;
    const unsigned* hb = hist + (size_t)b * NBINS;

    S[tid] = coarse[b * 256 + tid];
    __syncthreads();
    for (int off = 1; off < 256; off <<= 1) {   // suffix sum
        unsigned v = S[tid] + ((tid + off < 256) ? S[tid + off] : 0u);
        __syncthreads();
        S[tid] = v;
        __syncthreads();
    }
    if (S[tid] >= (unsigned)PRE && (tid == 255 || S[tid + 1] < (unsigned)PRE)) {
        Csh = tid;
        cumAbove = (tid == 255) ? 0u : S[tid + 1];
    }
    __syncthreads();
    int C = Csh; unsigned ca = cumAbove;
    unsigned f = hb[C * 256 + tid];
    __syncthreads();
    S[tid] = f;
    __syncthreads();
    for (int off = 1; off < 256; off <<= 1) {
        unsigned v = S[tid] + ((tid + off < 256) ? S[tid + off] : 0u);
        __syncthreads();
        S[tid] = v;
        __syncthreads();
    }
    if (ca + S[tid] >= (unsigned)PRE && (tid == 255 || ca + S[tid + 1] < (unsigned)PRE))
        T[b] = (unsigned)(C * 256 + tid);
}

// ---------------- kernel: compact candidates >= threshold bucket ----------------
__global__ __launch_bounds__(256) void k_compact(const float* __restrict__ scores,
                                                 const unsigned* __restrict__ T,
                                                 unsigned* __restrict__ cnt,
                                                 unsigned long long* __restrict__ cand)
{
    int m4 = blockIdx.x * 256 + threadIdx.x;
    int b = blockIdx.y;
    if (m4 >= NTOT / 4) return;
    float sv[4];
    *(float4*)sv = ((const float4*)(scores + (size_t)b * NTOT))[m4];
    unsigned Tb = T[b];
    #pragma unroll
    for (int k = 0; k < 4; k++) {
        unsigned u = fkey(sv[k]);
        if ((u >> 16) >= Tb) {
            int m = m4 * 4 + k;
            int n;
            if (m < 57600) { int a = m / 6400; int hw = m - a * 6400; n = hw * 9 + a; }
            else { int mm = m - 57600; int a = mm / 1600; int hw = mm - a * 1600; n = 57600 + hw * 9 + a; }
            unsigned pos = atomicAdd(&cnt[b], 1u);
            if (pos < CAP)
                cand[(size_t)b * CAP + pos] = ((unsigned long long)u << 32) | (unsigned)(~(unsigned)n);
        }
    }
}

// ---------------- kernel: per-image bitonic sort (runtime pow2) + gather ------
__global__ __launch_bounds__(1024) void k_sort(
    const unsigned long long* __restrict__ cand, const unsigned* __restrict__ cnt,
    const float* __restrict__ boxes, const float* __restrict__ scores, const float* __restrict__ cls,
    float* __restrict__ sboxes, float* __restrict__ sscores, float* __restrict__ scls)
{
    __shared__ unsigned long long keys[CAP];
    int b = blockIdx.x, tid = threadIdx.x;
    int c = min((int)cnt[b], CAP);
    int P = 1024;
    while (P < c) P <<= 1;
    for (int i = tid; i < P; i += 1024)
        keys[i] = (i < c) ? cand[(size_t)b * CAP + i] : 0ULL;

    for (int k2 = 2; k2 <= P; k2 <<= 1)
        for (int j = k2 >> 1; j > 0; j >>= 1) {
            __syncthreads();
            for (int i = tid; i < P; i += 1024) {
                int l = i ^ j;
                if (l > i) {
                    unsigned long long x = keys[i], y = keys[l];
                    bool up = ((i & k2) == 0);
                    if ((x > y) == up) { keys[i] = y; keys[l] = x; }
                }
            }
        }
    __syncthreads();

    if (tid < PRE) {
        unsigned long long key = keys[P - 1 - tid];       // descending
        int n = (int)~(unsigned)(key & 0xFFFFFFFFu);
        int m;
        if (n < 57600) { int hw = n / 9; int a = n - hw * 9; m = a * 6400 + hw; }
        else { int n2 = n - 57600; int hw = n2 / 9; int a = n2 - hw * 9; m = 57600 + a * 1600 + hw; }
        size_t src = (size_t)b * NTOT + m;
        ((float4*)sboxes)[b * 1024 + tid] = ((const float4*)boxes)[src];
        sscores[b * 1024 + tid] = scores[src];
        scls[b * 1024 + tid] = cls[src];
    }
}

// ---------------- kernel: suppression bitmask (1000 x 1000) ----------------
__global__ __launch_bounds__(1024) void k_mask(const float* __restrict__ sboxes,
                                               const float* __restrict__ sscores,
                                               unsigned long long* __restrict__ mask)
{
    __shared__ float4 bx[64];
    __shared__ float  sl[64];
    int b = blockIdx.y, w = blockIdx.x, tid = threadIdx.x;
    if (tid < 64) {
        int j = w * 64 + tid;
        bx[tid] = ((const float4*)sboxes)[b * 1024 + j];
        sl[tid] = sscores[b * 1024 + j];
    }
    __syncthreads();
    int r = tid;
    unsigned long long* dst = &mask[((size_t)(b * 1024) + r) * 16 + w];
    if (r >= PRE || w * 64 + 63 <= r) { *dst = 0ULL; return; }

    float4 br = ((const float4*)sboxes)[b * 1024 + r];
    float sr = sscores[b * 1024 + r];
    float arear = (br.z - br.x) * (br.w - br.y);
    unsigned long long bits = 0;
    int jend = min(64, PRE - w * 64);
    for (int jj = 0; jj < jend; jj++) {
        int j = w * 64 + jj;
        float4 bj = bx[jj];
        float ix1 = fmaxf(br.x, bj.x), iy1 = fmaxf(br.y, bj.y);
        float ix2 = fminf(br.z, bj.z), iy2 = fminf(br.w, bj.w);
        float iw = fmaxf(ix2 - ix1, 0.f), ih = fmaxf(iy2 - iy1, 0.f);
        float inter = iw * ih;
        float areaj = (bj.z - bj.x) * (bj.w - bj.y);
        float iou = inter / (arear + areaj - inter + 1e-9f);
        if (j > r && iou > 0.5f && sr > sl[jj]) bits |= 1ull << jj;
    }
    *dst = bits;
}

// ---------------- kernel: chunked greedy NMS + output (one wave per image) ----
__global__ __launch_bounds__(64) void k_nms(const unsigned long long* __restrict__ mask,
                                            const float* __restrict__ sboxes,
                                            const float* __restrict__ sscores,
                                            const float* __restrict__ scls,
                                            float* __restrict__ out)
{
    int b = blockIdx.x, lane = threadIdx.x;
    const unsigned long long* mrow = mask + (size_t)b * 1024 * 16;

    unsigned long long validw = 0;
    for (int w = 0; w < 16; w++) {
        int r = w * 64 + lane;
        bool v = false;
        if (r < PRE) {
            float sc = sscores[b * 1024 + r];
            float4 bbx = ((const float4*)sboxes)[b * 1024 + r];
            v = (sc >= 0.05f) && (bbx.x < bbx.z) && (bbx.y < bbx.w);
        }
        unsigned long long bal = __ballot(v);
        if (lane == w) validw = bal;
    }

    unsigned long long remv = 0, keepw = 0;

    for (int c = 0; c < 16; c++) {
        const unsigned long long* myrow = mrow + (size_t)(c * 64 + lane) * 16;
        unsigned long long m_cc = myrow[c];
        unsigned long long rw[16];
        rw[0] = 0;
        #pragma unroll
        for (int w = 1; w < 16; w++)
            rw[w] = (w > c) ? myrow[w] : 0ULL;

        unsigned long long cur = __shfl(validw & ~remv, c);
        unsigned long long todo = cur;
        while (todo) {
            int jj = __ffsll((unsigned long long)todo) - 1;
            unsigned long long row = __shfl(m_cc, jj);
            cur &= ~row;
            todo = (todo & (todo - 1)) & ~row;
        }
        if (lane == c) keepw = cur;

        bool mykept = ((cur >> lane) & 1ULL) != 0;
        #pragma unroll
        for (int w = 1; w < 16; w++) {
            if (w > c) {
                unsigned long long v = mykept ? rw[w] : 0ULL;
                v |= __shfl_xor(v, 32);
                v |= __shfl_xor(v, 16);
                v |= __shfl_xor(v, 8);
                v |= __shfl_xor(v, 4);
                v |= __shfl_xor(v, 2);
                v |= __shfl_xor(v, 1);
                if (lane == w) remv |= v;
            }
        }
    }

    __shared__ unsigned long long kws[16];
    __shared__ int pfx[17];
    if (lane < 16) kws[lane] = keepw;
    __syncthreads();
    if (lane == 0) {
        int s = 0;
        for (int w = 0; w < 16; w++) { pfx[w] = s; s += __popcll(kws[w]); }
        pfx[16] = s;
    }
    __syncthreads();
    int nk = pfx[16];

    float* ob = out;                       // [8][300][4]
    float* os = out + BB * POST * 4;       // [8][300]
    float* oc = os + BB * POST;            // [8][300]

    for (int r = lane; r < PRE; r += 64) {
        int w = r >> 6;
        unsigned long long kw = kws[w];
        if ((kw >> (r & 63)) & 1ULL) {
            int rank = pfx[w] + __popcll(kw & ((1ULL << (r & 63)) - 1ULL));
            if (rank < POST) {
                ((float4*)ob)[b * POST + rank] = ((const float4*)sboxes)[b * 1024 + r];
                os[b * POST + rank] = sscores[b * 1024 + r];
                oc[b * POST + rank] = scls[b * 1024 + r];
            }
        }
    }
    for (int p = nk + lane; p < POST; p += 64) {
        ((float4*)ob)[b * POST + p] = make_float4(0.f, 0.f, 0.f, 0.f);
        os[b * POST + p] = 0.f;
        oc[b * POST + p] = 0.f;
    }
}

// ---------------- launch ----------------
extern "C" void kernel_launch(void* const* d_in, const int* in_sizes, int n_in,
                              void* d_out, int out_size, void* d_ws, size_t ws_size,
                              hipStream_t stream)
{
    const float* data0 = (const float*)d_in[0];
    const float* data1 = (const float*)d_in[2];
    for (int i = 0; i < n_in; i++) {
        if (in_sizes[i] == 8 * 756 * 6400) data0 = (const float*)d_in[i];
        else if (in_sizes[i] == 8 * 756 * 1600) data1 = (const float*)d_in[i];
    }

    char* ws = (char*)d_ws;
    size_t off = 0;
    auto alloc = [&](size_t bytes) -> char* {
        char* p = ws + off;
        off = (off + bytes + 255) & ~(size_t)255;
        return p;
    };

    float* boxes   = (float*)alloc((size_t)BB * NTOT * 4 * 4);
    float* scores  = (float*)alloc((size_t)BB * NTOT * 4);
    float* cls     = (float*)alloc((size_t)BB * NTOT * 4);
    unsigned* hist = (unsigned*)alloc((size_t)BB * NBINS * 4);
    unsigned* cnt  = (unsigned*)alloc(BB * 4);          // directly after hist
    unsigned* T    = (unsigned*)alloc(BB * 4);
    unsigned* coarse = (unsigned*)alloc(BB * 256 * 4);
    unsigned long long* cand = (unsigned long long*)alloc((size_t)BB * CAP * 8);
    float* sboxes  = (float*)alloc((size_t)BB * 1024 * 4 * 4);
    float* sscores = (float*)alloc((size_t)BB * 1024 * 4);
    float* scls    = (float*)alloc((size_t)BB * 1024 * 4);
    unsigned long long* mask = (unsigned long long*)alloc((size_t)BB * 1024 * 16 * 8);
    unsigned long long* partial = (unsigned long long*)alloc((size_t)5 * 576000 * 8);
    float* dstage  = (float*)alloc((size_t)(DS1BASE + 72 * 4 * 1600) * 4);

    // zero hist + cnt (hist is 2 MB, 256-multiple; cnt follows)
    (void)hipMemsetAsync(hist, 0, (size_t)BB * NBINS * 4 + 256, stream);

    k_stream<<<NBLK0 + NBLK1, 256, 0, stream>>>(data0, data1, partial, dstage);

    k_cells<<<(288000 + 255) / 256, 256, 0, stream>>>(partial, dstage, boxes, scores, cls, hist);

    k_hsum<<<64, 256, 0, stream>>>(hist, coarse);
    k_thresh<<<BB, 256, 0, stream>>>(hist, coarse, T);

    dim3 g3((NTOT / 4 + 255) / 256, BB);
    k_compact<<<g3, 256, 0, stream>>>(scores, T, cnt, cand);

    k_sort<<<BB, 1024, 0, stream>>>(cand, cnt, boxes, scores, cls, sboxes, sscores, scls);

    dim3 g5(16, BB);
    k_mask<<<g5, 1024, 0, stream>>>(sboxes, sscores, mask);

    k_nms<<<BB, 64, 0, stream>>>(mask, sboxes, sscores, scls, (float*)d_out);
}

// Round 6
// 498.188 us; speedup vs baseline: 1.2984x; 1.2984x over previous
//
#include <hip/hip_runtime.h>
#include <math.h>

// Keep all float arithmetic un-contracted (separate mul/add like the numpy/jax
// f32 reference) so discrete decisions (argmax, top-k order, iou>thr) match.
#pragma clang fp contract(off)

// ---------------- problem constants ----------------
#define BB      8
#define AA      9
#define NCLS    80
#define NTOT    72000      // 57600 + 14400 boxes per image
#define PRE     1000
#define POST    300
#define CAP     4096
#define BCLIP   4.135166556742356f   // log(1000/16)
#define NBLK0   1440       // 72 slabs * 5 cgroups * 4 hw-quarters
#define NBLK1   360        // 72 slabs * 5 cgroups
#define DS1BASE 1843200    // float offset of branch1 delta staging (72*4*6400)

__device__ __constant__ float c_sizes[9] = {16.f,32.f,64.f,20.f,40.f,80.f,24.f,48.f,96.f};

__device__ inline unsigned fkey(float s) {
    unsigned u = __float_as_uint(s);
    return (u & 0x80000000u) ? ~u : (u | 0x80000000u);
}
__device__ inline float unfkey(unsigned u) {
    return __uint_as_float((u & 0x80000000u) ? (u ^ 0x80000000u) : ~u);
}

// ---------------- kernel A: contiguous stream + LDS class-max reduction --------
// Block owns (slab=(b,a), class-group cg, hw-chunk). Channel-sequential inner
// loop: no per-element division, delta-vs-score branch is uniform per channel,
// 8 float4 loads in flight per 4-channel batch.
template<int BR>
__device__ inline void stream_impl(int bx, const float* __restrict__ data,
                                   unsigned long long* __restrict__ partial,
                                   float* __restrict__ dstage,
                                   unsigned long long* lkey)
{
    constexpr int ROWF4 = BR ? 400 : 1600;   // channel row length in float4
    int slab, cg, hwq;
    if (BR == 0) { slab = bx / 20; int r = bx % 20; cg = r / 4; hwq = r % 4; }
    else         { slab = bx / 5;  cg = bx % 5;  hwq = 0; }
    int b = slab / 9, a = slab - (slab / 9) * 9;
    int nch = cg ? 16 : 20;
    int c_first = cg ? (4 + cg * 16) : 0;

    for (int i = threadIdx.x; i < 1600; i += 256) lkey[i] = 0ULL;
    __syncthreads();

    const float4* d4 = (const float4*)data;
    size_t rowbase = (size_t)(b * 756 + a * 84 + c_first) * ROWF4 + hwq * 400;
    float4* ds4 = (float4*)dstage;

    int tid = threadIdx.x;
    int rr2 = tid + 256;               // second strip (only tid<144 active)
    bool s2 = (rr2 < 400);

    for (int c0 = 0; c0 < nch; c0 += 4) {
        float4 v[8];
        #pragma unroll
        for (int u = 0; u < 4; u++) {
            size_t base = rowbase + (size_t)(c0 + u) * ROWF4;
            v[2 * u]     = d4[base + tid];
            v[2 * u + 1] = s2 ? d4[base + rr2] : make_float4(0.f, 0.f, 0.f, 0.f);
        }
        #pragma unroll
        for (int u = 0; u < 4; u++) {
            int ch = c_first + c0 + u;
            if (ch < 4) {              // uniform per u (cg0 batch0 is all-delta)
                size_t di0, di1;
                if (BR) { di0 = (size_t)(DS1BASE / 4) + (size_t)(slab * 4 + ch) * 400 + tid;
                          di1 = di0 + 256; }
                else    { di0 = (size_t)(slab * 4 + ch) * 1600 + hwq * 400 + tid;
                          di1 = di0 + 256; }
                ds4[di0] = v[2 * u];
                if (s2) ds4[di1] = v[2 * u + 1];
            } else {
                unsigned icls = ~(unsigned)(ch - 4);
                float4 x = v[2 * u];
                int cell = tid * 4;
                atomicMax(&lkey[cell + 0], ((unsigned long long)fkey(x.x) << 32) | icls);
                atomicMax(&lkey[cell + 1], ((unsigned long long)fkey(x.y) << 32) | icls);
                atomicMax(&lkey[cell + 2], ((unsigned long long)fkey(x.z) << 32) | icls);
                atomicMax(&lkey[cell + 3], ((unsigned long long)fkey(x.w) << 32) | icls);
                if (s2) {
                    float4 y = v[2 * u + 1];
                    int cell2 = rr2 * 4;
                    atomicMax(&lkey[cell2 + 0], ((unsigned long long)fkey(y.x) << 32) | icls);
                    atomicMax(&lkey[cell2 + 1], ((unsigned long long)fkey(y.y) << 32) | icls);
                    atomicMax(&lkey[cell2 + 2], ((unsigned long long)fkey(y.z) << 32) | icls);
                    atomicMax(&lkey[cell2 + 3], ((unsigned long long)fkey(y.w) << 32) | icls);
                }
            }
        }
    }
    __syncthreads();

    size_t pbase = (size_t)cg * 576000 + (size_t)b * 72000
                 + (BR ? (size_t)(57600 + a * 1600) : (size_t)(a * 6400 + hwq * 1600));
    for (int cell = threadIdx.x; cell < 1600; cell += 256)
        partial[pbase + cell] = lkey[cell];
}

__global__ __launch_bounds__(256) void k_stream(
    const float* __restrict__ data0, const float* __restrict__ data1,
    unsigned long long* __restrict__ partial, float* __restrict__ dstage)
{
    __shared__ unsigned long long lkey[1600];
    int bx = blockIdx.x;
    if (bx < NBLK0) stream_impl<0>(bx, data0, partial, dstage, lkey);
    else            stream_impl<1>(bx - NBLK0, data1, partial, dstage, lkey);
}

// ---------------- kernel B: merge partials + decode + LDS coarse hist ----------
__global__ __launch_bounds__(256) void k_cells(
    const unsigned long long* __restrict__ partial, const float* __restrict__ dstage,
    float* __restrict__ boxes, float* __restrict__ scores, float* __restrict__ cls,
    unsigned* __restrict__ chist)
{
    __shared__ unsigned lh[256];
    int tid = threadIdx.x;
    lh[tid] = 0;
    __syncthreads();

    int b = blockIdx.y;
    int mm = blockIdx.x * 256 + tid;             // pair index (2 cells)
    if (mm < 36000) {
        const ulonglong2* p2 = (const ulonglong2*)partial;
        ulonglong2 best = p2[(size_t)b * 36000 + mm];
        #pragma unroll
        for (int g = 1; g < 5; g++) {
            ulonglong2 v = p2[(size_t)g * 288000 + (size_t)b * 36000 + mm];
            if (v.x > best.x) best.x = v.x;
            if (v.y > best.y) best.y = v.y;
        }
        unsigned long long kk[2] = { best.x, best.y };

        int m0 = mm * 2;
        int a, hw, W, STRIDE;
        size_t dbase;
        if (m0 < 57600) {
            a = m0 / 6400; hw = m0 - a * 6400; W = 80; STRIDE = 8;
            dbase = (size_t)((b * 9 + a) * 4) * 6400 + hw;
        } else {
            int m1 = m0 - 57600;
            a = m1 / 1600; hw = m1 - a * 1600; W = 40; STRIDE = 16;
            dbase = (size_t)DS1BASE + (size_t)((b * 9 + a) * 4) * 1600 + hw;
        }
        size_t cstride = (m0 < 57600) ? 6400 : 1600;
        float2 dx = *(const float2*)(dstage + dbase);
        float2 dy = *(const float2*)(dstage + dbase + cstride);
        float2 dw = *(const float2*)(dstage + dbase + 2 * cstride);
        float2 dh = *(const float2*)(dstage + dbase + 3 * cstride);
        float dxa[2] = {dx.x, dx.y}, dya[2] = {dy.x, dy.y};
        float dwa[2] = {dw.x, dw.y}, dha[2] = {dh.x, dh.y};

        float sz = c_sizes[a];
        size_t o = (size_t)b * NTOT + m0;

        #pragma unroll
        for (int k = 0; k < 2; k++) {
            int hwk = hw + k;
            int h = hwk / W;
            int w = hwk - h * W;
            float cy = (h + 0.5f) * (float)STRIDE;
            float cx = (w + 0.5f) * (float)STRIDE;
            float pcx = dxa[k] * sz + cx;
            float pcy = dya[k] * sz + cy;
            float pw  = expf(fminf(dwa[k], BCLIP)) * sz;
            float ph  = expf(fminf(dha[k], BCLIP)) * sz;
            float x1 = fminf(fmaxf(pcx - 0.5f * pw, 0.f), 640.f);
            float y1 = fminf(fmaxf(pcy - 0.5f * ph, 0.f), 640.f);
            float x2 = fminf(fmaxf(pcx + 0.5f * pw, 0.f), 640.f);
            float y2 = fminf(fmaxf(pcy + 0.5f * ph, 0.f), 640.f);
            ((float4*)boxes)[o + k] = make_float4(x1, y1, x2, y2);
            scores[o + k] = unfkey((unsigned)(kk[k] >> 32));
            cls[o + k]    = (float)(~(unsigned)kk[k]);
            atomicAdd(&lh[(unsigned)(kk[k] >> 56)], 1u);
        }
    }
    __syncthreads();
    if (lh[tid]) atomicAdd(&chist[b * 256 + tid], lh[tid]);
}

// ---------------- kernel C1: coarse scan -> C, cumAbove ----------------
__global__ __launch_bounds__(256) void k_cscan(const unsigned* __restrict__ chist,
                                               unsigned* __restrict__ Cca)
{
    __shared__ unsigned S[256];
    int b = blockIdx.x, tid = threadIdx.x;
    S[tid] = chist[b * 256 + tid];
    __syncthreads();
    for (int off = 1; off < 256; off <<= 1) {   // suffix sum
        unsigned v = S[tid] + ((tid + off < 256) ? S[tid + off] : 0u);
        __syncthreads();
        S[tid] = v;
        __syncthreads();
    }
    if (S[tid] >= (unsigned)PRE && (tid == 255 || S[tid + 1] < (unsigned)PRE)) {
        Cca[b * 2]     = (unsigned)tid;
        Cca[b * 2 + 1] = (tid == 255) ? 0u : S[tid + 1];
    }
}

// ---------------- kernel C2: fine histogram of coarse-bucket-C items ----------
__global__ __launch_bounds__(256) void k_fine(const float* __restrict__ scores,
                                              const unsigned* __restrict__ Cca,
                                              unsigned* __restrict__ fhist)
{
    __shared__ unsigned lh[256];
    int tid = threadIdx.x;
    lh[tid] = 0;
    __syncthreads();
    int b = blockIdx.y;
    unsigned C = Cca[b * 2];
    int m4 = blockIdx.x * 256 + tid;
    if (m4 < NTOT / 4) {
        float sv[4];
        *(float4*)sv = ((const float4*)(scores + (size_t)b * NTOT))[m4];
        #pragma unroll
        for (int k = 0; k < 4; k++) {
            unsigned u = fkey(sv[k]);
            if ((u >> 24) == C) atomicAdd(&lh[(u >> 16) & 0xFF], 1u);
        }
    }
    __syncthreads();
    if (lh[tid]) atomicAdd(&fhist[b * 256 + tid], lh[tid]);
}

// ---------------- kernel C3: fine scan -> 16-bit threshold T ----------------
__global__ __launch_bounds__(256) void k_fthr(const unsigned* __restrict__ fhist,
                                              const unsigned* __restrict__ Cca,
                                              unsigned* __restrict__ T)
{
    __shared__ unsigned S[256];
    int b = blockIdx.x, tid = threadIdx.x;
    unsigned C = Cca[b * 2], ca = Cca[b * 2 + 1];
    S[tid] = fhist[b * 256 + tid];
    __syncthreads();
    for (int off = 1; off < 256; off <<= 1) {
        unsigned v = S[tid] + ((tid + off < 256) ? S[tid + off] : 0u);
        __syncthreads();
        S[tid] = v;
        __syncthreads();
    }
    if (ca + S[tid] >= (unsigned)PRE && (tid == 255 || ca + S[tid + 1] < (unsigned)PRE))
        T[b] = (C << 8) | (unsigned)tid;
}

// ---------------- kernel: compact candidates >= threshold bucket ----------------
__global__ __launch_bounds__(256) void k_compact(const float* __restrict__ scores,
                                                 const unsigned* __restrict__ T,
                                                 unsigned* __restrict__ cnt,
                                                 unsigned long long* __restrict__ cand)
{
    int m4 = blockIdx.x * 256 + threadIdx.x;
    int b = blockIdx.y;
    if (m4 >= NTOT / 4) return;
    float sv[4];
    *(float4*)sv = ((const float4*)(scores + (size_t)b * NTOT))[m4];
    unsigned Tb = T[b];
    #pragma unroll
    for (int k = 0; k < 4; k++) {
        unsigned u = fkey(sv[k]);
        if ((u >> 16) >= Tb) {
            int m = m4 * 4 + k;
            int n;
            if (m < 57600) { int a = m / 6400; int hw = m - a * 6400; n = hw * 9 + a; }
            else { int mm = m - 57600; int a = mm / 1600; int hw = mm - a * 1600; n = 57600 + hw * 9 + a; }
            unsigned pos = atomicAdd(&cnt[b], 1u);
            if (pos < CAP)
                cand[(size_t)b * CAP + pos] = ((unsigned long long)u << 32) | (unsigned)(~(unsigned)n);
        }
    }
}

// ---------------- kernel: per-image bitonic sort (runtime pow2) + gather ------
__global__ __launch_bounds__(1024) void k_sort(
    const unsigned long long* __restrict__ cand, const unsigned* __restrict__ cnt,
    const float* __restrict__ boxes, const float* __restrict__ scores, const float* __restrict__ cls,
    float* __restrict__ sboxes, float* __restrict__ sscores, float* __restrict__ scls)
{
    __shared__ unsigned long long keys[CAP];
    int b = blockIdx.x, tid = threadIdx.x;
    int c = min((int)cnt[b], CAP);
    int P = 1024;
    while (P < c) P <<= 1;
    for (int i = tid; i < P; i += 1024)
        keys[i] = (i < c) ? cand[(size_t)b * CAP + i] : 0ULL;

    for (int k2 = 2; k2 <= P; k2 <<= 1)
        for (int j = k2 >> 1; j > 0; j >>= 1) {
            __syncthreads();
            for (int i = tid; i < P; i += 1024) {
                int l = i ^ j;
                if (l > i) {
                    unsigned long long x = keys[i], y = keys[l];
                    bool up = ((i & k2) == 0);
                    if ((x > y) == up) { keys[i] = y; keys[l] = x; }
                }
            }
        }
    __syncthreads();

    if (tid < PRE) {
        unsigned long long key = keys[P - 1 - tid];       // descending
        int n = (int)~(unsigned)(key & 0xFFFFFFFFu);
        int m;
        if (n < 57600) { int hw = n / 9; int a = n - hw * 9; m = a * 6400 + hw; }
        else { int n2 = n - 57600; int hw = n2 / 9; int a = n2 - hw * 9; m = 57600 + a * 1600 + hw; }
        size_t src = (size_t)b * NTOT + m;
        ((float4*)sboxes)[b * 1024 + tid] = ((const float4*)boxes)[src];
        sscores[b * 1024 + tid] = scores[src];
        scls[b * 1024 + tid] = cls[src];
    }
}

// ---------------- kernel: suppression bitmask (1000 x 1000) ----------------
__global__ __launch_bounds__(1024) void k_mask(const float* __restrict__ sboxes,
                                               const float* __restrict__ sscores,
                                               unsigned long long* __restrict__ mask)
{
    __shared__ float4 bx[64];
    __shared__ float  sl[64];
    int b = blockIdx.y, w = blockIdx.x, tid = threadIdx.x;
    if (tid < 64) {
        int j = w * 64 + tid;
        bx[tid] = ((const float4*)sboxes)[b * 1024 + j];
        sl[tid] = sscores[b * 1024 + j];
    }
    __syncthreads();
    int r = tid;
    unsigned long long* dst = &mask[((size_t)(b * 1024) + r) * 16 + w];
    if (r >= PRE || w * 64 + 63 <= r) { *dst = 0ULL; return; }

    float4 br = ((const float4*)sboxes)[b * 1024 + r];
    float sr = sscores[b * 1024 + r];
    float arear = (br.z - br.x) * (br.w - br.y);
    unsigned long long bits = 0;
    int jend = min(64, PRE - w * 64);
    for (int jj = 0; jj < jend; jj++) {
        int j = w * 64 + jj;
        float4 bj = bx[jj];
        float ix1 = fmaxf(br.x, bj.x), iy1 = fmaxf(br.y, bj.y);
        float ix2 = fminf(br.z, bj.z), iy2 = fminf(br.w, bj.w);
        float iw = fmaxf(ix2 - ix1, 0.f), ih = fmaxf(iy2 - iy1, 0.f);
        float inter = iw * ih;
        float areaj = (bj.z - bj.x) * (bj.w - bj.y);
        float iou = inter / (arear + areaj - inter + 1e-9f);
        if (j > r && iou > 0.5f && sr > sl[jj]) bits |= 1ull << jj;
    }
    *dst = bits;
}

// ---------------- kernel: chunked greedy NMS + output (one wave per image) ----
__global__ __launch_bounds__(64) void k_nms(const unsigned long long* __restrict__ mask,
                                            const float* __restrict__ sboxes,
                                            const float* __restrict__ sscores,
                                            const float* __restrict__ scls,
                                            float* __restrict__ out)
{
    int b = blockIdx.x, lane = threadIdx.x;
    const unsigned long long* mrow = mask + (size_t)b * 1024 * 16;

    unsigned long long validw = 0;
    for (int w = 0; w < 16; w++) {
        int r = w * 64 + lane;
        bool v = false;
        if (r < PRE) {
            float sc = sscores[b * 1024 + r];
            float4 bbx = ((const float4*)sboxes)[b * 1024 + r];
            v = (sc >= 0.05f) && (bbx.x < bbx.z) && (bbx.y < bbx.w);
        }
        unsigned long long bal = __ballot(v);
        if (lane == w) validw = bal;
    }

    unsigned long long remv = 0, keepw = 0;

    for (int c = 0; c < 16; c++) {
        const unsigned long long* myrow = mrow + (size_t)(c * 64 + lane) * 16;
        unsigned long long m_cc = myrow[c];
        unsigned long long rw[16];
        rw[0] = 0;
        #pragma unroll
        for (int w = 1; w < 16; w++)
            rw[w] = (w > c) ? myrow[w] : 0ULL;

        unsigned long long cur = __shfl(validw & ~remv, c);
        unsigned long long todo = cur;
        while (todo) {
            int jj = __ffsll((unsigned long long)todo) - 1;
            unsigned long long row = __shfl(m_cc, jj);
            cur &= ~row;
            todo = (todo & (todo - 1)) & ~row;
        }
        if (lane == c) keepw = cur;

        bool mykept = ((cur >> lane) & 1ULL) != 0;
        #pragma unroll
        for (int w = 1; w < 16; w++) {
            if (w > c) {
                unsigned long long v = mykept ? rw[w] : 0ULL;
                v |= __shfl_xor(v, 32);
                v |= __shfl_xor(v, 16);
                v |= __shfl_xor(v, 8);
                v |= __shfl_xor(v, 4);
                v |= __shfl_xor(v, 2);
                v |= __shfl_xor(v, 1);
                if (lane == w) remv |= v;
            }
        }
    }

    __shared__ unsigned long long kws[16];
    __shared__ int pfx[17];
    if (lane < 16) kws[lane] = keepw;
    __syncthreads();
    if (lane == 0) {
        int s = 0;
        for (int w = 0; w < 16; w++) { pfx[w] = s; s += __popcll(kws[w]); }
        pfx[16] = s;
    }
    __syncthreads();
    int nk = pfx[16];

    float* ob = out;                       // [8][300][4]
    float* os = out + BB * POST * 4;       // [8][300]
    float* oc = os + BB * POST;            // [8][300]

    for (int r = lane; r < PRE; r += 64) {
        int w = r >> 6;
        unsigned long long kw = kws[w];
        if ((kw >> (r & 63)) & 1ULL) {
            int rank = pfx[w] + __popcll(kw & ((1ULL << (r & 63)) - 1ULL));
            if (rank < POST) {
                ((float4*)ob)[b * POST + rank] = ((const float4*)sboxes)[b * 1024 + r];
                os[b * POST + rank] = sscores[b * 1024 + r];
                oc[b * POST + rank] = scls[b * 1024 + r];
            }
        }
    }
    for (int p = nk + lane; p < POST; p += 64) {
        ((float4*)ob)[b * POST + p] = make_float4(0.f, 0.f, 0.f, 0.f);
        os[b * POST + p] = 0.f;
        oc[b * POST + p] = 0.f;
    }
}

// ---------------- launch ----------------
extern "C" void kernel_launch(void* const* d_in, const int* in_sizes, int n_in,
                              void* d_out, int out_size, void* d_ws, size_t ws_size,
                              hipStream_t stream)
{
    const float* data0 = (const float*)d_in[0];
    const float* data1 = (const float*)d_in[2];
    for (int i = 0; i < n_in; i++) {
        if (in_sizes[i] == 8 * 756 * 6400) data0 = (const float*)d_in[i];
        else if (in_sizes[i] == 8 * 756 * 1600) data1 = (const float*)d_in[i];
    }

    char* ws = (char*)d_ws;
    size_t off = 0;
    auto alloc = [&](size_t bytes) -> char* {
        char* p = ws + off;
        off = (off + bytes + 255) & ~(size_t)255;
        return p;
    };

    float* boxes   = (float*)alloc((size_t)BB * NTOT * 4 * 4);
    float* scores  = (float*)alloc((size_t)BB * NTOT * 4);
    float* cls     = (float*)alloc((size_t)BB * NTOT * 4);
    // zero-init group (contiguous): cnt(256B pad) + chist(8K) + fhist(8K)
    unsigned* cnt   = (unsigned*)alloc(BB * 4);
    unsigned* chist = (unsigned*)alloc(BB * 256 * 4);
    unsigned* fhist = (unsigned*)alloc(BB * 256 * 4);
    unsigned* Cca  = (unsigned*)alloc(BB * 2 * 4);
    unsigned* T    = (unsigned*)alloc(BB * 4);
    unsigned long long* cand = (unsigned long long*)alloc((size_t)BB * CAP * 8);
    float* sboxes  = (float*)alloc((size_t)BB * 1024 * 4 * 4);
    float* sscores = (float*)alloc((size_t)BB * 1024 * 4);
    float* scls    = (float*)alloc((size_t)BB * 1024 * 4);
    unsigned long long* mask = (unsigned long long*)alloc((size_t)BB * 1024 * 16 * 8);
    unsigned long long* partial = (unsigned long long*)alloc((size_t)5 * 576000 * 8);
    float* dstage  = (float*)alloc((size_t)(DS1BASE + 72 * 4 * 1600) * 4);

    (void)hipMemsetAsync(cnt, 0, 256 + 2 * (size_t)BB * 256 * 4, stream);

    k_stream<<<NBLK0 + NBLK1, 256, 0, stream>>>(data0, data1, partial, dstage);

    dim3 gc(141, BB);
    k_cells<<<gc, 256, 0, stream>>>(partial, dstage, boxes, scores, cls, chist);

    k_cscan<<<BB, 256, 0, stream>>>(chist, Cca);
    dim3 gf((NTOT / 4 + 255) / 256, BB);
    k_fine<<<gf, 256, 0, stream>>>(scores, Cca, fhist);
    k_fthr<<<BB, 256, 0, stream>>>(fhist, Cca, T);

    k_compact<<<gf, 256, 0, stream>>>(scores, T, cnt, cand);

    k_sort<<<BB, 1024, 0, stream>>>(cand, cnt, boxes, scores, cls, sboxes, sscores, scls);

    dim3 g5(16, BB);
    k_mask<<<g5, 1024, 0, stream>>>(sboxes, sscores, mask);

    k_nms<<<BB, 64, 0, stream>>>(mask, sboxes, sscores, scls, (float*)d_out);
}